// Round 5
// baseline (419.626 us; speedup 1.0000x reference)
//
#include <hip/hip_runtime.h>
#include <hip/hip_bf16.h>
#include <cstdint>
#include <cstddef>

typedef __bf16 bf16x8 __attribute__((ext_vector_type(8)));
typedef float f32x4 __attribute__((ext_vector_type(4)));

#define AS1(p) ((const __attribute__((address_space(1))) void*)(p))
#define AS3(p) ((__attribute__((address_space(3))) void*)(p))
#define LDSA(p) ((unsigned)(size_t)(const __attribute__((address_space(3))) unsigned short*)(p))

__device__ __forceinline__ unsigned short f2bf_rne(float f) {
    union { float f; unsigned u; } c; c.f = f;
    unsigned u = c.u;
    unsigned r = (u + 0x7FFFu + ((u >> 16) & 1u)) >> 16;
    return (unsigned short)r;
}

// -------- binarize: one block per output row; sign -> bf16 bits, alpha = mean|w| --------
__global__ __launch_bounds__(256)
void binarize_k(const float* __restrict__ W, unsigned short* __restrict__ Sg,
                float* __restrict__ Alpha, int C) {
    const int r = blockIdx.x;
    const float4* w = (const float4*)(W + (size_t)r * C);
    ushort4* s = (ushort4*)(Sg + (size_t)r * C);
    const int n4 = C >> 2;
    float lsum = 0.f;
    for (int i = threadIdx.x; i < n4; i += 256) {
        float4 v = w[i];
        lsum += fabsf(v.x) + fabsf(v.y) + fabsf(v.z) + fabsf(v.w);
        ushort4 o;
        o.x = (v.x == 0.f) ? 0 : ((v.x < 0.f) ? 0xBF80 : 0x3F80);
        o.y = (v.y == 0.f) ? 0 : ((v.y < 0.f) ? 0xBF80 : 0x3F80);
        o.z = (v.z == 0.f) ? 0 : ((v.z < 0.f) ? 0xBF80 : 0x3F80);
        o.w = (v.w == 0.f) ? 0 : ((v.w < 0.f) ? 0xBF80 : 0x3F80);
        s[i] = o;
    }
    for (int o = 32; o > 0; o >>= 1) lsum += __shfl_down(lsum, o, 64);
    __shared__ float red[4];
    const int lane = threadIdx.x & 63, wid = threadIdx.x >> 6;
    if (lane == 0) red[wid] = lsum;
    __syncthreads();
    if (threadIdx.x == 0) Alpha[r] = (red[0] + red[1] + red[2] + red[3]) / (float)C;
}

// -------- fp32 -> bf16 convert (vectorized) --------
__global__ __launch_bounds__(256)
void f32_to_bf16_k(const float* __restrict__ X, unsigned short* __restrict__ Y, int n4) {
    const int stride = gridDim.x * 256;
    for (int i = blockIdx.x * 256 + threadIdx.x; i < n4; i += stride) {
        float4 v = ((const float4*)X)[i];
        ushort4 o;
        o.x = f2bf_rne(v.x); o.y = f2bf_rne(v.y);
        o.z = f2bf_rne(v.z); o.w = f2bf_rne(v.w);
        ((ushort4*)Y)[i] = o;
    }
}

// ======== GEMM1: 256x256 8-phase (asm ds_read, single rule-#18 fence) ========
// The ONLY change vs r3: no trailing sched_barrier(0) after the MFMA cluster,
// so next-phase ds_read/STAGE issues can execute under the MFMA shadow.
template<int GELU>
__global__ __launch_bounds__(512, 2)
void gemm_bin8(const unsigned short* __restrict__ A,
               const unsigned short* __restrict__ S,
               const float* __restrict__ alpha,
               const float* __restrict__ bias,
               unsigned short* __restrict__ Obf,
               float* __restrict__ Of32,
               int M, int N, int K)
{
    __shared__ __align__(16) unsigned short lds[2][2][2][128 * 64];

    const int tid  = threadIdx.x;
    const int lane = tid & 63;
    const int wid  = tid >> 6;
    const int wr   = wid >> 2;
    const int wc   = wid & 3;
    const int lr   = lane & 15;
    const int hi   = lane >> 4;
    const int xorv = lr & 7;

    const int nbn = N >> 8, nbm = M >> 8;
    const int nwg = nbm * nbn;
    const int q = nwg >> 3, r = nwg & 7;
    const int xcd = blockIdx.x & 7, loc = blockIdx.x >> 3;
    const int swz = (xcd < r ? xcd * (q + 1) : r * (q + 1) + (xcd - r) * q) + loc;
    const int bm = swz / nbn, bn = swz % nbn;

    const unsigned short* gA = A + (size_t)bm * 256 * K;
    const unsigned short* gB = S + (size_t)bn * 256 * K;

    const unsigned short* Ab[2] = { &lds[0][0][wr][0], &lds[1][0][wr][0] };
    const unsigned short* Bb[2] = { &lds[0][1][wc >> 1][0], &lds[1][1][wc >> 1][0] };
    const int brow = (wc & 1) * 64;

    f32x4 acc[8][4] = {};
    bf16x8 af[2][4], bq0[2][2], bq1[2][2];

    const int T = K >> 6;
    const int niter = T >> 1;

#define STAGE(BUF_, MAT_, HALF_, TILE_, GSRC_) do {                                   \
    const unsigned short* _g = (GSRC_) + (size_t)(HALF_) * 128 * K + ((TILE_) << 6);  \
    unsigned short* _l = &lds[BUF_][MAT_][HALF_][0];                                  \
    _Pragma("unroll")                                                                 \
    for (int _rd = 0; _rd < 2; ++_rd) {                                               \
        const int _u = _rd * 512 + tid;                                               \
        const int _row = _u >> 3;                                                     \
        const int _sc = ((_u & 7) ^ (_row & 7)) << 3;                                 \
        __builtin_amdgcn_global_load_lds(AS1(_g + (size_t)_row * K + _sc),            \
                                         AS3(_l + _u * 8), 16, 0, 0);                 \
    }                                                                                 \
} while (0)

#define DSR(DST_, PTR_) do {                                                          \
    f32x4 _t;                                                                         \
    asm volatile("ds_read_b128 %0, %1" : "=v"(_t) : "v"(LDSA(PTR_)));                 \
    DST_ = __builtin_bit_cast(bf16x8, _t);                                            \
} while (0)

#define LOAD_AF(BUF_, MB_) do {                                                       \
    _Pragma("unroll")                                                                 \
    for (int _ks = 0; _ks < 2; ++_ks)                                                 \
    _Pragma("unroll")                                                                 \
    for (int _mf = 0; _mf < 4; ++_mf)                                                 \
        DSR(af[_ks][_mf], Ab[BUF_] + (((MB_)*4 + _mf) * 16 + lr) * 64                 \
                          + (((_ks << 2) + hi) ^ xorv) * 8);                          \
} while (0)

#define LOAD_BF(ARR_, BUF_, NB_) do {                                                 \
    _Pragma("unroll")                                                                 \
    for (int _ks = 0; _ks < 2; ++_ks)                                                 \
    _Pragma("unroll")                                                                 \
    for (int _nf = 0; _nf < 2; ++_nf)                                                 \
        DSR(ARR_[_ks][_nf], Bb[BUF_] + (brow + ((NB_)*2 + _nf) * 16 + lr) * 64        \
                            + (((_ks << 2) + hi) ^ xorv) * 8);                        \
} while (0)

#define MFMA_Q(MB_, ARR_, NB_) do {                                                   \
    _Pragma("unroll")                                                                 \
    for (int _ks = 0; _ks < 2; ++_ks)                                                 \
    _Pragma("unroll")                                                                 \
    for (int _mf = 0; _mf < 4; ++_mf)                                                 \
    _Pragma("unroll")                                                                 \
    for (int _nf = 0; _nf < 2; ++_nf)                                                 \
        acc[(MB_)*4 + _mf][(NB_)*2 + _nf] = __builtin_amdgcn_mfma_f32_16x16x32_bf16(  \
            af[_ks][_mf], ARR_[_ks][_nf], acc[(MB_)*4 + _mf][(NB_)*2 + _nf], 0, 0, 0);\
} while (0)

#define BAR() __builtin_amdgcn_s_barrier()
#define VMW4() asm volatile("s_waitcnt vmcnt(4)" ::: "memory")
#define LGKM0() do {                                                                  \
    asm volatile("s_waitcnt lgkmcnt(0)" ::: "memory");                                \
    __builtin_amdgcn_sched_barrier(0);                                                \
} while (0)
// MFMA phase: rule-#18 fence only; MFMAs free to drain past BAR2 while the
// next phase's ds_read/STAGE issues overlap.
#define MFMA_PHASE(MB_, ARR_, NB_) do {                                               \
    BAR(); LGKM0();                                                                   \
    __builtin_amdgcn_s_setprio(1);                                                    \
    MFMA_Q(MB_, ARR_, NB_);                                                           \
    __builtin_amdgcn_s_setprio(0);                                                    \
    BAR();                                                                            \
} while (0)

    STAGE(0, 1, 0, 0, gB); STAGE(0, 1, 1, 0, gB);
    STAGE(0, 0, 0, 0, gA); STAGE(0, 0, 1, 0, gA);
    STAGE(1, 1, 0, 1, gB); STAGE(1, 1, 1, 1, gB);
    VMW4();
    BAR();

    for (int i = 0; i < niter; ++i) {
        const int t  = 2 * i;
        const int t1 = t + 1;
        const int t2 = (t + 2 < T) ? t + 2 : 0;
        const int t3 = (t + 3 < T) ? t + 3 : 1;

        LOAD_AF(0, 0); LOAD_BF(bq0, 0, 0);
        STAGE(1, 0, 0, t1, gA);
        MFMA_PHASE(0, bq0, 0);

        LOAD_BF(bq1, 0, 1);
        STAGE(1, 0, 1, t1, gA);
        MFMA_PHASE(0, bq1, 1);

        LOAD_AF(0, 1);
        STAGE(0, 1, 0, t2, gB);
        MFMA_PHASE(1, bq0, 0);

        STAGE(0, 1, 1, t2, gB);
        BAR(); LGKM0();
        __builtin_amdgcn_s_setprio(1);
        MFMA_Q(1, bq1, 1);
        __builtin_amdgcn_s_setprio(0);
        VMW4(); BAR();

        LOAD_AF(1, 0); LOAD_BF(bq0, 1, 0);
        STAGE(0, 0, 0, t2, gA);
        MFMA_PHASE(0, bq0, 0);

        LOAD_BF(bq1, 1, 1);
        STAGE(0, 0, 1, t2, gA);
        MFMA_PHASE(0, bq1, 1);

        LOAD_AF(1, 1);
        STAGE(1, 1, 0, t3, gB);
        MFMA_PHASE(1, bq0, 0);

        STAGE(1, 1, 1, t3, gB);
        BAR(); LGKM0();
        __builtin_amdgcn_s_setprio(1);
        MFMA_Q(1, bq1, 1);
        __builtin_amdgcn_s_setprio(0);
        VMW4(); BAR();
    }

    const int col0 = bn * 256 + wc * 64;
    const int row0 = bm * 256 + wr * 128;
    float al[4], bi[4];
#pragma unroll
    for (int nf = 0; nf < 4; ++nf) {
        const int n = col0 + nf * 16 + lr;
        al[nf] = alpha[n];
        bi[nf] = bias[n];
    }
#pragma unroll
    for (int mf = 0; mf < 8; ++mf) {
#pragma unroll
        for (int j = 0; j < 4; ++j) {
            const int m = row0 + mf * 16 + hi * 4 + j;
#pragma unroll
            for (int nf = 0; nf < 4; ++nf) {
                const int n = col0 + nf * 16 + lr;
                float v = acc[mf][nf][j] * al[nf] + bi[nf];
                if (GELU) {
                    v = 0.5f * v * (1.0f + erff(v * 0.70710678118654752f));
                    Obf[(size_t)m * N + n] = f2bf_rne(v);
                } else {
                    Of32[(size_t)m * N + n] = v;
                }
            }
        }
    }
#undef STAGE
#undef DSR
#undef LOAD_AF
#undef LOAD_BF
#undef MFMA_Q
#undef BAR
#undef VMW4
#undef LGKM0
#undef MFMA_PHASE
}

// ======== GEMM2: r4's proven 2-phase, BM=128/BN=64 (hedge, unchanged) ========
template<int GELU, int BN>
__global__ __launch_bounds__(256)
void gemm_bin(const unsigned short* __restrict__ A,
              const unsigned short* __restrict__ S,
              const float* __restrict__ alpha,
              const float* __restrict__ bias,
              unsigned short* __restrict__ Obf,
              float* __restrict__ Of32,
              int M, int N, int K)
{
    constexpr int WN = BN / 2;
    constexpr int NFRAG = WN / 16;

    __shared__ __align__(16) unsigned short As[128 * 64];
    __shared__ __align__(16) unsigned short Ss[BN * 64];

    const int tid  = threadIdx.x;
    const int lane = tid & 63;
    const int wid  = tid >> 6;
    const int wr   = wid >> 1, wc = wid & 1;
    const int lr   = lane & 15;
    const int hi   = lane >> 4;
    const int xorv = lr & 7;

    const int nbn = N / BN, nbm = M >> 7;
    const int nwg = nbm * nbn;
    const int q = nwg >> 3, r = nwg & 7;
    const int xcd = blockIdx.x & 7, loc = blockIdx.x >> 3;
    const int swz = (xcd < r ? xcd * (q + 1) : r * (q + 1) + (xcd - r) * q) + loc;
    const int bm = swz / nbn, bn = swz % nbn;

    const unsigned short* gA = A + (size_t)bm * 128 * K;
    const unsigned short* gS = S + (size_t)bn * BN * K;

    f32x4 acc[4][NFRAG] = {};

    const int nkt = K >> 6;
    for (int kt = 0; kt < nkt; ++kt) {
        const int k0 = kt << 6;
#pragma unroll
        for (int j = 0; j < 4; ++j) {
            const int u = j * 256 + tid;
            const int row = u >> 3;
            const int sc = ((u & 7) ^ (row & 7)) << 3;
            __builtin_amdgcn_global_load_lds(AS1(gA + (size_t)row * K + k0 + sc),
                                             AS3(&As[0] + u * 8), 16, 0, 0);
        }
#pragma unroll
        for (int j = 0; j < BN / 32; ++j) {
            const int u = j * 256 + tid;
            const int row = u >> 3;
            const int sc = ((u & 7) ^ (row & 7)) << 3;
            __builtin_amdgcn_global_load_lds(AS1(gS + (size_t)row * K + k0 + sc),
                                             AS3(&Ss[0] + u * 8), 16, 0, 0);
        }
        __syncthreads();

        bf16x8 af[2][4], bf[2][NFRAG];
#pragma unroll
        for (int ks = 0; ks < 2; ++ks) {
            const int kg = ((ks << 2) + hi) ^ xorv;
#pragma unroll
            for (int mf = 0; mf < 4; ++mf)
                af[ks][mf] = *(const bf16x8*)(&As[0] + (wr * 64 + mf * 16 + lr) * 64 + kg * 8);
#pragma unroll
            for (int nf = 0; nf < NFRAG; ++nf)
                bf[ks][nf] = *(const bf16x8*)(&Ss[0] + (wc * WN + nf * 16 + lr) * 64 + kg * 8);
        }
#pragma unroll
        for (int ks = 0; ks < 2; ++ks)
#pragma unroll
            for (int mf = 0; mf < 4; ++mf)
#pragma unroll
                for (int nf = 0; nf < NFRAG; ++nf)
                    acc[mf][nf] = __builtin_amdgcn_mfma_f32_16x16x32_bf16(
                        af[ks][mf], bf[ks][nf], acc[mf][nf], 0, 0, 0);
        __syncthreads();
    }

    const int col0 = bn * BN + wc * WN;
    const int row0 = bm * 128 + wr * 64;
    float al[NFRAG], bi[NFRAG];
#pragma unroll
    for (int nf = 0; nf < NFRAG; ++nf) {
        const int n = col0 + nf * 16 + lr;
        al[nf] = alpha[n];
        bi[nf] = bias[n];
    }
#pragma unroll
    for (int mf = 0; mf < 4; ++mf) {
#pragma unroll
        for (int j = 0; j < 4; ++j) {
            const int m = row0 + mf * 16 + hi * 4 + j;
#pragma unroll
            for (int nf = 0; nf < NFRAG; ++nf) {
                const int n = col0 + nf * 16 + lr;
                float v = acc[mf][nf][j] * al[nf] + bi[nf];
                if (GELU) {
                    v = 0.5f * v * (1.0f + erff(v * 0.70710678118654752f));
                    Obf[(size_t)m * N + n] = f2bf_rne(v);
                } else {
                    Of32[(size_t)m * N + n] = v;
                }
            }
        }
    }
}

extern "C" void kernel_launch(void* const* d_in, const int* in_sizes, int n_in,
                              void* d_out, int out_size, void* d_ws, size_t ws_size,
                              hipStream_t stream) {
    const float* x  = (const float*)d_in[0];
    const float* w1 = (const float*)d_in[1];
    const float* b1 = (const float*)d_in[2];
    const float* w2 = (const float*)d_in[3];
    const float* b2 = (const float*)d_in[4];
    float* out = (float*)d_out;

    const int D = 1024, H = 4096;
    const int M = in_sizes[0] / D;   // 12544

    char* ws = (char*)d_ws;
    size_t off = 0;
    auto alloc = [&](size_t bytes) -> void* {
        void* p = ws + off;
        off = (off + bytes + 255) & ~(size_t)255;
        return p;
    };
    unsigned short* xb = (unsigned short*)alloc((size_t)M * D * 2);
    unsigned short* s1 = (unsigned short*)alloc((size_t)H * D * 2);
    float*          a1 = (float*)alloc((size_t)H * 4);
    unsigned short* s2 = (unsigned short*)alloc((size_t)D * H * 2);
    float*          a2 = (float*)alloc((size_t)D * 4);
    unsigned short* hb = (unsigned short*)alloc((size_t)M * H * 2);

    binarize_k<<<H, 256, 0, stream>>>(w1, s1, a1, D);
    binarize_k<<<D, 256, 0, stream>>>(w2, s2, a2, H);
    f32_to_bf16_k<<<2048, 256, 0, stream>>>(x, xb, (M * D) / 4);

    gemm_bin8<1><<<(M / 256) * (H / 256), 512, 0, stream>>>(xb, s1, a1, b1, hb, nullptr, M, H, D);
    gemm_bin<0, 64><<<(M / 128) * (D / 64), 256, 0, stream>>>(hb, s2, a2, b2, nullptr, out, M, D, H);
}

// Round 7
// 382.844 us; speedup vs baseline: 1.0961x; 1.0961x over previous
//
#include <hip/hip_runtime.h>
#include <hip/hip_bf16.h>
#include <cstdint>
#include <cstddef>

typedef __bf16 bf16x8 __attribute__((ext_vector_type(8)));
typedef float f32x4 __attribute__((ext_vector_type(4)));

#define AS1(p) ((const __attribute__((address_space(1))) void*)(p))
#define AS3(p) ((__attribute__((address_space(3))) void*)(p))

__device__ __forceinline__ unsigned short f2bf_rne(float f) {
    union { float f; unsigned u; } c; c.f = f;
    unsigned u = c.u;
    unsigned r = (u + 0x7FFFu + ((u >> 16) & 1u)) >> 16;
    return (unsigned short)r;
}

// tanh-form GELU, NaN-free: g = v - v/(e^{2u}+1), 2u = v*(C1 + C2*v^2)
// max |diff vs exact erf-GELU| ~5e-4 (at |v|~2.5); stateless & deterministic.
__device__ __forceinline__ float gelu_fast(float v) {
    const float C1 = 1.5957691216057308f;    // 2*sqrt(2/pi)
    const float C2 = 0.07135481627247335f;   // 2*sqrt(2/pi)*0.044715
    float vv = v * v;
    float U = v * __builtin_fmaf(C2, vv, C1);      // 2u
    float t = __expf(U);                            // e^{2u}
    return v - v * __builtin_amdgcn_rcpf(t + 1.0f);
}

// -------- binarize: one block per output row; sign -> bf16 bits, alpha = mean|w| --------
__global__ __launch_bounds__(256)
void binarize_k(const float* __restrict__ W, unsigned short* __restrict__ Sg,
                float* __restrict__ Alpha, int C) {
    const int r = blockIdx.x;
    const float4* w = (const float4*)(W + (size_t)r * C);
    ushort4* s = (ushort4*)(Sg + (size_t)r * C);
    const int n4 = C >> 2;
    float lsum = 0.f;
    for (int i = threadIdx.x; i < n4; i += 256) {
        float4 v = w[i];
        lsum += fabsf(v.x) + fabsf(v.y) + fabsf(v.z) + fabsf(v.w);
        ushort4 o;
        o.x = (v.x == 0.f) ? 0 : ((v.x < 0.f) ? 0xBF80 : 0x3F80);
        o.y = (v.y == 0.f) ? 0 : ((v.y < 0.f) ? 0xBF80 : 0x3F80);
        o.z = (v.z == 0.f) ? 0 : ((v.z < 0.f) ? 0xBF80 : 0x3F80);
        o.w = (v.w == 0.f) ? 0 : ((v.w < 0.f) ? 0xBF80 : 0x3F80);
        s[i] = o;
    }
    for (int o = 32; o > 0; o >>= 1) lsum += __shfl_down(lsum, o, 64);
    __shared__ float red[4];
    const int lane = threadIdx.x & 63, wid = threadIdx.x >> 6;
    if (lane == 0) red[wid] = lsum;
    __syncthreads();
    if (threadIdx.x == 0) Alpha[r] = (red[0] + red[1] + red[2] + red[3]) / (float)C;
}

// -------- fp32 -> bf16 convert (vectorized) --------
__global__ __launch_bounds__(256)
void f32_to_bf16_k(const float* __restrict__ X, unsigned short* __restrict__ Y, int n4) {
    const int stride = gridDim.x * 256;
    for (int i = blockIdx.x * 256 + threadIdx.x; i < n4; i += stride) {
        float4 v = ((const float4*)X)[i];
        ushort4 o;
        o.x = f2bf_rne(v.x); o.y = f2bf_rne(v.y);
        o.z = f2bf_rne(v.z); o.w = f2bf_rne(v.w);
        ((ushort4*)Y)[i] = o;
    }
}

// -------- binary-weight GEMM, m97 structure + conflict-free xor swizzle (r4-exact) --------
// C[m,n] = act(alpha[n] * sum_k A[m,k]*S[n,k] + bias[n])
// A bf16 [M,K] row-major; S bf16 sign [N,K] row-major (B^T layout).
// BM=128, BN in {128,64}, BK=64, 256 thr = 4 waves (2x2).
// LDS [R][64] col-slot xor swizzle (slot ^ row&7): pre-swizzled global source,
// linear global_load_lds dest, same xor on read -> 0 bank conflicts.
template<int GELU, int BN>
__global__ __launch_bounds__(256)
void gemm_bin(const unsigned short* __restrict__ A,
              const unsigned short* __restrict__ S,
              const float* __restrict__ alpha,
              const float* __restrict__ bias,
              unsigned short* __restrict__ Obf,
              float* __restrict__ Of32,
              int M, int N, int K)
{
    constexpr int WN = BN / 2;
    constexpr int NFRAG = WN / 16;

    __shared__ __align__(16) unsigned short As[128 * 64];
    __shared__ __align__(16) unsigned short Ss[BN * 64];

    const int tid  = threadIdx.x;
    const int lane = tid & 63;
    const int wid  = tid >> 6;
    const int wr   = wid >> 1, wc = wid & 1;
    const int lr   = lane & 15;
    const int hi   = lane >> 4;
    const int xorv = lr & 7;

    // bijective XCD-aware block swizzle (m204 form)
    const int nbn = N / BN, nbm = M >> 7;
    const int nwg = nbm * nbn;
    const int q = nwg >> 3, r = nwg & 7;
    const int xcd = blockIdx.x & 7, loc = blockIdx.x >> 3;
    const int swz = (xcd < r ? xcd * (q + 1) : r * (q + 1) + (xcd - r) * q) + loc;
    const int bm = swz / nbn, bn = swz % nbn;

    const unsigned short* gA = A + (size_t)bm * 128 * K;
    const unsigned short* gS = S + (size_t)bn * BN * K;

    f32x4 acc[4][NFRAG] = {};

    const int nkt = K >> 6;
    for (int kt = 0; kt < nkt; ++kt) {
        const int k0 = kt << 6;
#pragma unroll
        for (int j = 0; j < 4; ++j) {
            const int u = j * 256 + tid;
            const int row = u >> 3;
            const int sc = ((u & 7) ^ (row & 7)) << 3;
            __builtin_amdgcn_global_load_lds(AS1(gA + (size_t)row * K + k0 + sc),
                                             AS3(&As[0] + u * 8), 16, 0, 0);
        }
#pragma unroll
        for (int j = 0; j < BN / 32; ++j) {
            const int u = j * 256 + tid;
            const int row = u >> 3;
            const int sc = ((u & 7) ^ (row & 7)) << 3;
            __builtin_amdgcn_global_load_lds(AS1(gS + (size_t)row * K + k0 + sc),
                                             AS3(&Ss[0] + u * 8), 16, 0, 0);
        }
        __syncthreads();

        bf16x8 af[2][4], bf[2][NFRAG];
#pragma unroll
        for (int ks = 0; ks < 2; ++ks) {
            const int kg = ((ks << 2) + hi) ^ xorv;
#pragma unroll
            for (int mf = 0; mf < 4; ++mf)
                af[ks][mf] = *(const bf16x8*)(&As[0] + (wr * 64 + mf * 16 + lr) * 64 + kg * 8);
#pragma unroll
            for (int nf = 0; nf < NFRAG; ++nf)
                bf[ks][nf] = *(const bf16x8*)(&Ss[0] + (wc * WN + nf * 16 + lr) * 64 + kg * 8);
        }
#pragma unroll
        for (int ks = 0; ks < 2; ++ks)
#pragma unroll
            for (int mf = 0; mf < 4; ++mf)
#pragma unroll
                for (int nf = 0; nf < NFRAG; ++nf)
                    acc[mf][nf] = __builtin_amdgcn_mfma_f32_16x16x32_bf16(
                        af[ks][mf], bf[ks][nf], acc[mf][nf], 0, 0, 0);
        __syncthreads();
    }

    // epilogue: alpha*acc + bias, optional fast GELU, store
    const int col0 = bn * BN + wc * WN;
    const int row0 = bm * 128 + wr * 64;
    float al[NFRAG], bi[NFRAG];
#pragma unroll
    for (int nf = 0; nf < NFRAG; ++nf) {
        const int n = col0 + nf * 16 + lr;
        al[nf] = alpha[n];
        bi[nf] = bias[n];
    }
#pragma unroll
    for (int mf = 0; mf < 4; ++mf) {
#pragma unroll
        for (int j = 0; j < 4; ++j) {
            const int m = row0 + mf * 16 + hi * 4 + j;
#pragma unroll
            for (int nf = 0; nf < NFRAG; ++nf) {
                const int n = col0 + nf * 16 + lr;
                float v = acc[mf][nf][j] * al[nf] + bi[nf];
                if (GELU) {
                    Obf[(size_t)m * N + n] = f2bf_rne(gelu_fast(v));
                } else {
                    Of32[(size_t)m * N + n] = v;
                }
            }
        }
    }
}

extern "C" void kernel_launch(void* const* d_in, const int* in_sizes, int n_in,
                              void* d_out, int out_size, void* d_ws, size_t ws_size,
                              hipStream_t stream) {
    const float* x  = (const float*)d_in[0];
    const float* w1 = (const float*)d_in[1];
    const float* b1 = (const float*)d_in[2];
    const float* w2 = (const float*)d_in[3];
    const float* b2 = (const float*)d_in[4];
    float* out = (float*)d_out;

    const int D = 1024, H = 4096;
    const int M = in_sizes[0] / D;   // 12544

    char* ws = (char*)d_ws;
    size_t off = 0;
    auto alloc = [&](size_t bytes) -> void* {
        void* p = ws + off;
        off = (off + bytes + 255) & ~(size_t)255;
        return p;
    };
    unsigned short* xb = (unsigned short*)alloc((size_t)M * D * 2);
    unsigned short* s1 = (unsigned short*)alloc((size_t)H * D * 2);
    float*          a1 = (float*)alloc((size_t)H * 4);
    unsigned short* s2 = (unsigned short*)alloc((size_t)D * H * 2);
    float*          a2 = (float*)alloc((size_t)D * 4);
    unsigned short* hb = (unsigned short*)alloc((size_t)M * H * 2);

    binarize_k<<<H, 256, 0, stream>>>(w1, s1, a1, D);
    binarize_k<<<D, 256, 0, stream>>>(w2, s2, a2, H);
    f32_to_bf16_k<<<2048, 256, 0, stream>>>(x, xb, (M * D) / 4);

    gemm_bin<1, 128><<<(M / 128) * (H / 128), 256, 0, stream>>>(xb, s1, a1, b1, hb, nullptr, M, H, D);
    gemm_bin<0, 64><<<(M / 128) * (D / 64), 256, 0, stream>>>(hb, s2, a2, b2, nullptr, out, M, D, H);
}